// Round 18
// baseline (389.771 us; speedup 1.0000x reference)
//
#include <hip/hip_runtime.h>

// TDT loss, fixed shapes from setup_inputs():
#define TDT_B  8
#define TDT_T  256
#define TDT_U  64
#define TDT_U1 65
#define TDT_V1 513   // V+1, blank index = 512
#define TP     275   // 4 zero-pad slices + 256 + slack
#define SIG    0.05f
#define SHIFT  3.0f  // exponent shift PER TIME-STEP: duration-d weight carries SHIFT*d
#define GC_STRIDE 340  // padded per-b GC stride (DMA 64-lane overreach stays in-bounds)

// ws layout (floats):
//   WB: float4[B][TP][U1]      = exp(lpb + ld_i - SIG + SHIFT*(i+1))
//   WY: float4[B][TP][U]       = exp(lpy + ld_i - SIG + SHIFT*(i+1))
//   GC: float4[B][GC_STRIDE]   = WB[b][tp][u=64] (padded; garbage past tp=259 ok)
//   CNT: unsigned[256]         = per-t-slice completion flags
#define OFF_PYD 572000                        // 8*275*65*4
#define OFF_GC  1135200                       // + 8*275*64*4
#define OFF_CNT 1146112                       // + 8*340*4 = 10880 -> 1146080, round up

// Zero slice flags + out (ws poisoned once, never re-poisoned between replays).
__global__ __launch_bounds__(256) void k_zero(float* __restrict__ out,
                                              unsigned* __restrict__ cnt) {
  cnt[threadIdx.x] = 0u;
  if (threadIdx.x == 0) out[0] = 0.f;
}

// DPP wave_shr:1 (ctrl 0x138), bound_ctrl=1 -> lane 0 reads 0.
__device__ __forceinline__ float shup1(float x) {
  const int r = __builtin_amdgcn_update_dpp(
      0, __float_as_int(x), 0x138, 0xf, 0xf, true);
  return __int_as_float(r);
}
// v_readlane: SGPR broadcast (serial renorm path).
__device__ __forceinline__ float rdlane(float x, int lane) {
  return __int_as_float(__builtin_amdgcn_readlane(__float_as_int(x), lane));
}
// Direct HBM->LDS DMA, 16B/lane: lane l -> ldsbase + l*16.
__device__ __forceinline__ void gl2lds16(const float4* g, float4* lds) {
  __builtin_amdgcn_global_load_lds(
      (const __attribute__((address_space(1))) void*)g,
      (__attribute__((address_space(3))) void*)lds, 16, 0, 0);
}
// Fill ring third j%3 with group j (slices 15j+1..15j+15); waves 1-3, 10 DMA each.
__device__ __forceinline__ void fill_group(
    const float4* __restrict__ WB4p, const float4* __restrict__ WY4p,
    float4* ring, int j, int wv, int l)
{
  const int sb = 15 * j + wv;
  const int rb = 15 * (j % 3) + (wv - 1);
#pragma unroll
  for (int k = 0; k < 5; ++k) {
    const int s    = sb + 3 * k;
    const int slot = rb + 3 * k;
    gl2lds16(WB4p + (size_t)s * TDT_U1 + l, ring + slot * 128);
    gl2lds16(WY4p + (size_t)s * TDT_U  + l, ring + slot * 128 + 64);
  }
}

// Fused producer/consumer kernel. Grid = 256 blocks (ALL co-resident: 97KB
// LDS -> 1 block/CU -> dispatch order irrelevant, no deadlock possible).
//   blocks 0..7   : consumer DP, one per b (4 waves: wv0 chain, wv1-3 loaders)
//   blocks 8..255 : producers, one t-slice each (p<8 also handle t=248+p).
// Producer: 520 rows/slice (130/wave), full 513-label log-softmax per row,
// write W records, __syncthreads, ONE agent-release flag store per slice
// (256 total -- R8's failure was 133k of these).
// Consumer loaders gate each group's DMA on the 15 slice flags: parallel
// relaxed atomic loads (lane per flag) + __all ballot + one __threadfence
// acquire per group, placed BEFORE the DMA issue so the counted-vmcnt
// pipeline (T3/T4) across the barrier is preserved.
__global__ __launch_bounds__(256, 1) void k_fused(
    const float* __restrict__ la, const float* __restrict__ da,
    const int* __restrict__ tgt, float* __restrict__ ws,
    float* __restrict__ out)
{
  unsigned* cnt = (unsigned*)(ws + OFF_CNT);
  const int wv = threadIdx.x >> 6;
  const int l  = threadIdx.x & 63;

  if (blockIdx.x >= 8) {
    // ---------------- producer: one (or two) t-slices per block ----------
    const int p = blockIdx.x - 8;           // 0..247
    const int nrep = (p < 8) ? 2 : 1;
    for (int rep = 0; rep < nrep; ++rep) {
      const int t = rep ? (248 + p) : p;
      for (int k = 0; k < 130; ++k) {
        const int idx = wv * 130 + k;       // 0..519
        const int b = idx / 65;
        const int u = idx - b * 65;
        const int r = (b * TDT_T + t) * TDT_U1 + u;

        const float* row = la + (size_t)r * TDT_V1;
        const int ofs = r & 1;              // odd rows: +1 for 8B align
        const float2* p2 = (const float2*)(row + ofs);
        float2 w[4];
#pragma unroll
        for (int q = 0; q < 4; ++q) w[q] = p2[l + (q << 6)];
        const float extra = row[ofs ? 0 : 512];

        float m = extra;
#pragma unroll
        for (int q = 0; q < 4; ++q) m = fmaxf(m, fmaxf(w[q].x, w[q].y));
#pragma unroll
        for (int off = 32; off; off >>= 1) m = fmaxf(m, __shfl_xor(m, off));
        float s = (l == 0) ? __expf(extra - m) : 0.f;
#pragma unroll
        for (int q = 0; q < 4; ++q) s += __expf(w[q].x - m) + __expf(w[q].y - m);
#pragma unroll
        for (int off = 32; off; off >>= 1) s += __shfl_xor(s, off);
        const float lse = m + __logf(s);

        const float4 dv = *(const float4*)(da + ((size_t)r << 2));
        const float m4 = fmaxf(fmaxf(dv.x, dv.y), fmaxf(dv.z, dv.w));
        const float l4 = m4 + __logf(__expf(dv.x - m4) + __expf(dv.y - m4) +
                                     __expf(dv.z - m4) + __expf(dv.w - m4));
        const float d0 = dv.x - l4 + SHIFT * 1.0f;
        const float d1 = dv.y - l4 + SHIFT * 2.0f;
        const float d2 = dv.z - l4 + SHIFT * 3.0f;
        const float d3 = dv.w - l4 + SHIFT * 4.0f;

        float4* WB4 = (float4*)ws;
        float4* WY4 = (float4*)(ws + OFF_PYD);
        float4* GC4 = (float4*)(ws + OFF_GC);
        const int tp = t + 4;

        const float xb = ofs ? w[3].y : extra;
        if (l == (ofs ? 63 : 0)) {
          const float pb = xb - lse - SIG;
          const float4 wb = make_float4(__expf(pb + d0), __expf(pb + d1),
                                        __expf(pb + d2), __expf(pb + d3));
          WB4[(b * TP + tp) * TDT_U1 + u] = wb;
          if (u == TDT_U) GC4[b * GC_STRIDE + tp] = wb;
        }

        const int tg = (u < TDT_U) ? tgt[b * TDT_U + u] : -1;
        bool own = false; float vt = 0.f;
#pragma unroll
        for (int q = 0; q < 4; ++q) {
          const int base = ofs + ((l + (q << 6)) << 1);
          if (base == tg)     { vt = w[q].x; own = true; }
          if (base + 1 == tg) { vt = w[q].y; own = true; }
        }
        if (ofs && tg == 0 && l == 0) { vt = extra; own = true; }
        if (own) {
          const float py = vt - lse - SIG;
          WY4[(b * TP + tp) * TDT_U + u] =
              make_float4(__expf(py + d0), __expf(py + d1),
                          __expf(py + d2), __expf(py + d3));
        }

        if (t < 4 && l == 0) {              // zero pads at tp = t
          const float4 z4 = make_float4(0.f, 0.f, 0.f, 0.f);
          WB4[(b * TP + t) * TDT_U1 + u] = z4;
          if (u == TDT_U) GC4[b * GC_STRIDE + t] = z4;
          if (u < TDT_U)  WY4[(b * TP + t) * TDT_U + u] = z4;
        }
      }
      __syncthreads();                      // drain block stores (vmcnt(0))
      if (threadIdx.x == 0)
        __hip_atomic_store(&cnt[t], 1u, __ATOMIC_RELEASE,
                           __HIP_MEMORY_SCOPE_AGENT);
    }
    return;
  }

  // ---------------- consumer: forward DP for b = blockIdx.x --------------
  const int b = blockIdx.x;
  const float4* WB4p = (const float4*)ws + (size_t)b * (TP * TDT_U1);
  const float4* WY4p = (const float4*)(ws + OFF_PYD) + (size_t)b * (TP * TDT_U);
  const float4* GC4p = (const float4*)(ws + OFF_GC) + (size_t)b * GC_STRIDE;

  extern __shared__ float4 smem[];          // 45*128 ring + 320 G = 97280 B
  float4* ring = smem;
  float4* glds = smem + 45 * 128;

  // parallel flag poll: lane (s-lo) watches cnt[s]; one acquire fence after
#define POLLG(LO, HI) do {                                                   \
    const int _lo = (LO), _hi = (HI);                                        \
    const bool _need = (l <= _hi - _lo);                                     \
    for (;;) {                                                               \
      unsigned v = 1u;                                                       \
      if (_need) v = __hip_atomic_load(&cnt[_lo + l], __ATOMIC_RELAXED,      \
                                       __HIP_MEMORY_SCOPE_AGENT);           \
      if (__all(v != 0)) break;                                              \
      __builtin_amdgcn_s_sleep(4);                                           \
    }                                                                        \
    __threadfence();                                                         \
  } while (0)

  // prologue: groups 0,1 (tp 1..30 -> flags t 0..26) + their G entries
  if (wv != 0) {
    POLLG(0, 26);
    fill_group(WB4p, WY4p, ring, 0, wv, l);
    fill_group(WB4p, WY4p, ring, 1, wv, l);
    if (wv == 1) {
      gl2lds16(GC4p + 1 + l,  glds + 1);    // glds[1..64]
      gl2lds16(GC4p + 16 + l, glds + 16);   // glds[16..79] (later fills overwrite)
    }
  }
  __syncthreads();

  // depth-15 FIFO: slot(s) = s%15 holds slice s
  float4 B0,B1,B2,B3,B4,B5,B6,B7,B8,B9,B10,B11,B12,B13,B14;
  float4 Y0,Y1,Y2,Y3,Y4,Y5,Y6,Y7,Y8,Y9,Y10,Y11,Y12,Y13,Y14;
  float4 G0,G1,G2,G3,G4,G5,G6,G7,G8,G9,G10,G11,G12,G13,G14;
  float a1 = 0.f, a2 = 0.f, a3 = 0.f, a4 = 0.f;
  float c1 = 0.f, c2 = 0.f, c3 = 0.f, c4 = 0.f;
  float L = 0.f;

#define LOADSLOT(S, RS, TPI) do {            \
    const int _r = (RS) * 128;               \
    B##S = ring[_r + l];                     \
    Y##S = ring[_r + 64 + l];                \
    G##S = glds[TPI];                        \
  } while (0)

  if (wv == 0) {
    LOADSLOT(1, 0, 1);   LOADSLOT(2, 1, 2);   LOADSLOT(3, 2, 3);
    LOADSLOT(4, 3, 4);   LOADSLOT(5, 4, 5);   LOADSLOT(6, 5, 6);
    LOADSLOT(7, 6, 7);   LOADSLOT(8, 7, 8);   LOADSLOT(9, 8, 9);
    LOADSLOT(10, 9, 10); LOADSLOT(11, 10, 11);LOADSLOT(12, 11, 12);
    LOADSLOT(13, 12, 13);LOADSLOT(14, 13, 14);LOADSLOT(0, 14, 15);
    a1 = (l == 0) ? 1.f : 0.f;               // A = exp(alpha + SHIFT*t - L)
  }

#define STEP(S0,S1,S2,S3, RSL, TPI) do {                                     \
    float p01 = fmaf(a2, Y##S1.y, a1 * Y##S0.x);                             \
    float p23 = fmaf(a4, Y##S3.w, a3 * Y##S2.z);                             \
    float P   = p01 + p23;                                                   \
    float m   = shup1(P);                                                    \
    float b01 = fmaf(a2, B##S1.y, a1 * B##S0.x);                             \
    float b23 = fmaf(a4, B##S3.w, a3 * B##S2.z);                             \
    float q01 = fmaf(c2, G##S1.y, c1 * G##S0.x);                             \
    float q23 = fmaf(c4, G##S3.w, c3 * G##S2.z);                             \
    float anew = (b01 + b23) + m;                                            \
    float cnew = (q01 + q23) + P;                                            \
    a4 = a3; a3 = a2; a2 = a1; a1 = anew;                                    \
    c4 = c3; c3 = c2; c2 = c1; c1 = cnew;                                    \
    LOADSLOT(S3, RSL, TPI);                                                  \
  } while (0)

  for (int i = 0, tb = 1; i < 17; ++i, tb += 15) {
    if (wv != 0) {
      if (i <= 15) {
        const int j = i + 2;
        const int hi = (15 * j + 11 < 255) ? (15 * j + 11) : 255;
        POLLG(15 * j - 3, hi);              // gate BEFORE issue (drain is old)
        fill_group(WB4p, WY4p, ring, j, wv, l);
        if (wv == 1) {
          gl2lds16(GC4p + 15 * j + 1 + l, glds + 15 * j + 1);
          asm volatile("s_waitcnt vmcnt(11)" ::: "memory"); // fill(i+1) done
        } else {
          asm volatile("s_waitcnt vmcnt(10)" ::: "memory");
        }
      } else {
        asm volatile("s_waitcnt vmcnt(0)" ::: "memory");    // drain tail
      }
      __builtin_amdgcn_sched_barrier(0);
      __builtin_amdgcn_s_barrier();
    } else {
      __builtin_amdgcn_sched_barrier(0);
      __builtin_amdgcn_s_barrier();
      __builtin_amdgcn_sched_barrier(0);
      if (i) {
        const float r1 = rdlane(a1, tb >> 3);
        const float r2 = rdlane(a1, tb >> 2);
        const float rl = fmaxf(r1, r2);
        const float sc = (rl > 1e-30f) ? (1.0f / rl) : 1.0f;
        L -= __logf(sc);
        a1 *= sc; a2 *= sc; a3 *= sc; a4 *= sc;
        c1 *= sc; c2 *= sc; c3 *= sc; c4 *= sc;
      }
      const int rbB = 15 * ((i + 1) % 3);
      STEP(4,3,2,1,     rbB + 0,  tb + 15);
      STEP(5,4,3,2,     rbB + 1,  tb + 16);
      STEP(6,5,4,3,     rbB + 2,  tb + 17);
      STEP(7,6,5,4,     rbB + 3,  tb + 18);
      STEP(8,7,6,5,     rbB + 4,  tb + 19);
      STEP(9,8,7,6,     rbB + 5,  tb + 20);
      STEP(10,9,8,7,    rbB + 6,  tb + 21);
      STEP(11,10,9,8,   rbB + 7,  tb + 22);
      STEP(12,11,10,9,  rbB + 8,  tb + 23);
      STEP(13,12,11,10, rbB + 9,  tb + 24);
      STEP(14,13,12,11, rbB + 10, tb + 25);
      STEP(0,14,13,12,  rbB + 11, tb + 26);
      STEP(1,0,14,13,   rbB + 12, tb + 27);
      STEP(2,1,0,14,    rbB + 13, tb + 28);
      STEP(3,2,1,0,     rbB + 14, tb + 29);
    }
  }

  if (wv == 0 && l == 63) {
    // ll = L - SHIFT*256 + log( sum_d C[256-d] * WG_d )
    const float sum = c1 * glds[259].x
                    + c2 * glds[258].y
                    + c3 * glds[257].z
                    + c4 * glds[256].w;
    const float ll = L - SHIFT * 256.0f + __logf(sum);
    atomicAdd(out, ll * (-1.0f / TDT_B));
  }
#undef STEP
#undef LOADSLOT
#undef POLLG
}

extern "C" void kernel_launch(void* const* d_in, const int* in_sizes, int n_in,
                              void* d_out, int out_size, void* d_ws, size_t ws_size,
                              hipStream_t stream)
{
  const float* la = (const float*)d_in[0];   // label_acts    (B,T,U+1,V+1) f32
  const float* da = (const float*)d_in[1];   // duration_acts (B,T,U+1,D)   f32
  const int*   tg = (const int*)d_in[2];     // targets       (B,U)         i32
  float* ws  = (float*)d_ws;
  float* out = (float*)d_out;

  unsigned* cnt = (unsigned*)(ws + OFF_CNT);
  k_zero <<<1, 256, 0, stream>>>(out, cnt);
  k_fused<<<256, 256, (45 * 128 + 320) * sizeof(float4), stream>>>(la, da, tg, ws, out);
}

// Round 19
// 77.233 us; speedup vs baseline: 5.0467x; 5.0467x over previous
//
#include <hip/hip_runtime.h>

// TDT loss, fixed shapes from setup_inputs():
#define TDT_B  8
#define TDT_T  256
#define TDT_U  64
#define TDT_U1 65
#define TDT_V1 513   // V+1, blank index = 512
#define TP     275   // 4 zero-pad slices + 256 + slack
#define SIG    0.05f
#define SHIFT  3.0f  // exponent shift PER TIME-STEP: duration-d weight carries SHIFT*d

// ws layout (floats):
//   WB: float4[B][TP][U1] = exp(lpb + ld_i - SIG + SHIFT*(i+1))
//   WY: float4[B][TP][U]  = exp(lpy + ld_i - SIG + SHIFT*(i+1))
//   GC: float4[B][TP]     = WB[b][tp][u=64]  (compact G column)
#define OFF_PYD 572000                        // 8*275*65*4
#define OFF_GC  1135200                       // + 8*275*64*4; GC = 8800 floats

// Kernel 1: per-(b,t,u) row log-softmax over 513 labels (wave per row, float2
// loads with odd-row alignment shim -- proven 47us version), duration
// log-softmax over 4, EXP-DOMAIN W records with per-duration e^{SHIFT*d}.
__global__ __launch_bounds__(256) void k_prep(
    const float* __restrict__ la, const float* __restrict__ da,
    const int* __restrict__ tgt, float* __restrict__ ws,
    float* __restrict__ out)
{
  if (blockIdx.x == 0 && threadIdx.x == 0) out[0] = 0.f;

  const int l = threadIdx.x & 63;
  const int r = (blockIdx.x << 2) + (threadIdx.x >> 6);   // row in [0, B*T*U1)
  const int u  = r % TDT_U1;
  const int bt = r / TDT_U1;
  const int t  = bt & (TDT_T - 1);
  const int b  = bt >> 8;

  const float* row = la + (size_t)r * TDT_V1;
  const int ofs = r & 1;                    // odd rows: shift by 1 for 8B align
  const float2* p2 = (const float2*)(row + ofs);
  float2 w[4];
#pragma unroll
  for (int k = 0; k < 4; ++k) w[k] = p2[l + (k << 6)];  // elems ofs+2l+128k+{0,1}
  const float extra = row[ofs ? 0 : 512];   // the one element outside the vec span

  float m = extra;
#pragma unroll
  for (int k = 0; k < 4; ++k) m = fmaxf(m, fmaxf(w[k].x, w[k].y));
#pragma unroll
  for (int off = 32; off; off >>= 1) m = fmaxf(m, __shfl_xor(m, off));
  float s = (l == 0) ? __expf(extra - m) : 0.f;
#pragma unroll
  for (int k = 0; k < 4; ++k) s += __expf(w[k].x - m) + __expf(w[k].y - m);
#pragma unroll
  for (int off = 32; off; off >>= 1) s += __shfl_xor(s, off);
  const float lse = m + __logf(s);

  // duration log-softmax (uniform per wave)
  const float4 dv = *(const float4*)(da + ((size_t)r << 2));
  const float m4 = fmaxf(fmaxf(dv.x, dv.y), fmaxf(dv.z, dv.w));
  const float l4 = m4 + __logf(__expf(dv.x - m4) + __expf(dv.y - m4) +
                               __expf(dv.z - m4) + __expf(dv.w - m4));
  // per-duration: ld_i - l4 + SHIFT*(i+1)  (scale-consistent exp domain)
  const float d0 = dv.x - l4 + SHIFT * 1.0f;
  const float d1 = dv.y - l4 + SHIFT * 2.0f;
  const float d2 = dv.z - l4 + SHIFT * 3.0f;
  const float d3 = dv.w - l4 + SHIFT * 4.0f;

  float4* WB4 = (float4*)ws;
  float4* WY4 = (float4*)(ws + OFF_PYD);
  float4* GC4 = (float4*)(ws + OFF_GC);

  const int tp = t + 4;
  // blank logit = elem 512: ofs==0 -> extra (owner lane 0); ofs==1 -> w[3].y (lane 63)
  const float xb = ofs ? w[3].y : extra;
  if (l == (ofs ? 63 : 0)) {
    const float pb = xb - lse - SIG;
    const float4 wb = make_float4(__expf(pb + d0), __expf(pb + d1),
                                  __expf(pb + d2), __expf(pb + d3));
    WB4[(b * TP + tp) * TDT_U1 + u] = wb;
    if (u == TDT_U) GC4[b * TP + tp] = wb;
  }

  // target gather (exactly one lane owns it); static indices only
  const int tg = (u < TDT_U) ? tgt[b * TDT_U + u] : -1;   // tg in [0,512)
  bool own = false; float vt = 0.f;
#pragma unroll
  for (int k = 0; k < 4; ++k) {
    const int base = ofs + ((l + (k << 6)) << 1);
    if (base == tg)     { vt = w[k].x; own = true; }
    if (base + 1 == tg) { vt = w[k].y; own = true; }
  }
  if (ofs && tg == 0 && l == 0) { vt = extra; own = true; }
  if (own) {
    const float py = vt - lse - SIG;
    WY4[(b * TP + tp) * TDT_U + u] =
        make_float4(__expf(py + d0), __expf(py + d1), __expf(py + d2), __expf(py + d3));
  }

  // zero pads for tau < 0 (slices tp = 0..3): exp(-inf) = 0
  if (t < 4 && l == 0) {
    const float4 z4 = make_float4(0.f, 0.f, 0.f, 0.f);
    WB4[(b * TP + t) * TDT_U1 + u] = z4;
    if (u == TDT_U) GC4[b * TP + t] = z4;
    if (u < TDT_U)  WY4[(b * TP + t) * TDT_U + u] = z4;
  }
}

// DPP wave_shr:1 (ctrl 0x138), bound_ctrl=1 -> lane 0 reads 0. VALU-pipe
// lane shift on the serial t-chain.
__device__ __forceinline__ float shup1(float x) {
  const int r = __builtin_amdgcn_update_dpp(
      0, __float_as_int(x), 0x138, 0xf, 0xf, true);
  return __int_as_float(r);
}

// v_readlane: SGPR broadcast, no LDS round-trip (serial renorm path).
__device__ __forceinline__ float rdlane(float x, int lane) {
  return __int_as_float(__builtin_amdgcn_readlane(__float_as_int(x), lane));
}

// Direct HBM->LDS DMA, 16B/lane: lane l's data lands at ldsbase + l*16.
__device__ __forceinline__ void gl2lds16(const float4* g, float4* lds) {
  __builtin_amdgcn_global_load_lds(
      (const __attribute__((address_space(1))) void*)g,
      (__attribute__((address_space(3))) void*)lds, 16, 0, 0);
}

// Loader helper: fill group j (slices 15j+1 .. 15j+15) into ring third j%3.
// Slice s -> ring slot (s-1)%45; slot holds B[u=0..63] then Y[u=0..63].
// Waves 1..3 own 5 interleaved slices each = 10 DMA per wave.
__device__ __forceinline__ void fill_group(
    const float4* __restrict__ WB4p, const float4* __restrict__ WY4p,
    float4* ring, int j, int wv, int l)
{
  const int sb = 15 * j + wv;               // this wave's first slice in group
  const int rb = 15 * (j % 3) + (wv - 1);   // its first ring slot
#pragma unroll
  for (int k = 0; k < 5; ++k) {
    const int s    = sb + 3 * k;
    const int slot = rb + 3 * k;
    gl2lds16(WB4p + (size_t)s * TDT_U1 + l, ring + slot * 128);
    gl2lds16(WY4p + (size_t)s * TDT_U  + l, ring + slot * 128 + 64);
  }
}

// Kernel 2: forward DP, exp domain. 8 blocks (one per b) x 4 waves.
// Wave 0: serial chain, depth-15 named FIFO (lead-12), ds_read from the
// 45-slice LDS ring; P-sum + fma step; readlane renorm.
// Waves 1-3: DMA-stream one group ahead.
// T3/T4: RAW s_barrier + COUNTED s_waitcnt vmcnt(10) on the loader waves --
// fill(i+2) stays in flight across the barrier; the wait covers only
// fill(i+1), issued a full iteration (~1400 cyc) earlier, so cold
// remote-L2/L3 latency is hidden. Ring-third disjointness under in-flight
// DMA: fill(i+2) writes third (i+2)%3; chain reads third (i+1)%3 at iter i
// -- never the same third. Prologue keeps one full __syncthreads drain.
__global__ __launch_bounds__(256, 1) void k_dp(
    const float* __restrict__ ws, float* __restrict__ out)
{
  const int b  = blockIdx.x;
  const int wv = threadIdx.x >> 6;
  const int l  = threadIdx.x & 63;
  const float4* WB4p = (const float4*)ws + (size_t)b * (TP * TDT_U1);
  const float4* WY4p = (const float4*)(ws + OFF_PYD) + (size_t)b * (TP * TDT_U);
  const float4* GC4p = (const float4*)(ws + OFF_GC) + (size_t)b * TP;

  extern __shared__ float4 smem[];          // 45*128 ring + 275 G = 96.6 KB
  float4* ring = smem;
  float4* glds = smem + 45 * 128;

  // prologue: G column (lane-variant vector loads) + groups 0,1; full drain
  if (wv != 0) {
    for (int i = (threadIdx.x - 64); i < TP; i += 192) glds[i] = GC4p[i];
    fill_group(WB4p, WY4p, ring, 0, wv, l);
    fill_group(WB4p, WY4p, ring, 1, wv, l);
  }
  __syncthreads();

  // depth-15 FIFO: slot(s) = s%15 holds slice s
  float4 B0,B1,B2,B3,B4,B5,B6,B7,B8,B9,B10,B11,B12,B13,B14;
  float4 Y0,Y1,Y2,Y3,Y4,Y5,Y6,Y7,Y8,Y9,Y10,Y11,Y12,Y13,Y14;
  float4 G0,G1,G2,G3,G4,G5,G6,G7,G8,G9,G10,G11,G12,G13,G14;
  float a1 = 0.f, a2 = 0.f, a3 = 0.f, a4 = 0.f;
  float c1 = 0.f, c2 = 0.f, c3 = 0.f, c4 = 0.f;
  float L = 0.f;

#define LOADSLOT(S, RS, TPI) do {            \
    const int _r = (RS) * 128;               \
    B##S = ring[_r + l];                     \
    Y##S = ring[_r + 64 + l];                \
    G##S = glds[TPI];                        \
  } while (0)

  if (wv == 0) {
    // preload slices 1..15 (ring slots 0..14, third 0) into FIFO slot s%15
    LOADSLOT(1, 0, 1);   LOADSLOT(2, 1, 2);   LOADSLOT(3, 2, 3);
    LOADSLOT(4, 3, 4);   LOADSLOT(5, 4, 5);   LOADSLOT(6, 5, 6);
    LOADSLOT(7, 6, 7);   LOADSLOT(8, 7, 8);   LOADSLOT(9, 8, 9);
    LOADSLOT(10, 9, 10); LOADSLOT(11, 10, 11);LOADSLOT(12, 11, 12);
    LOADSLOT(13, 12, 13);LOADSLOT(14, 13, 14);LOADSLOT(0, 14, 15);
    a1 = (l == 0) ? 1.f : 0.f;               // A = exp(alpha + SHIFT*t - L)
  }

  // step t: FIFO slots (t+3)%15..t%15 supply slices t+3..t; then load slice
  // t+15 from ring slot (t+14)%45 into FIFO slot t%15 (=S3). Lead-12.
#define STEP(S0,S1,S2,S3, RSL, TPI) do {                                     \
    float p01 = fmaf(a2, Y##S1.y, a1 * Y##S0.x);                             \
    float p23 = fmaf(a4, Y##S3.w, a3 * Y##S2.z);                             \
    float P   = p01 + p23;                                                   \
    float m   = shup1(P);                                                    \
    float b01 = fmaf(a2, B##S1.y, a1 * B##S0.x);                             \
    float b23 = fmaf(a4, B##S3.w, a3 * B##S2.z);                             \
    float q01 = fmaf(c2, G##S1.y, c1 * G##S0.x);                             \
    float q23 = fmaf(c4, G##S3.w, c3 * G##S2.z);                             \
    float anew = (b01 + b23) + m;                                            \
    float cnew = (q01 + q23) + P;                                            \
    a4 = a3; a3 = a2; a2 = a1; a1 = anew;                                    \
    c4 = c3; c3 = c2; c2 = c1; c1 = cnew;                                    \
    LOADSLOT(S3, RSL, TPI);                                                  \
  } while (0)

  for (int i = 0, tb = 1; i < 17; ++i, tb += 15) {
    if (wv != 0) {
      // producer: issue next group, COUNTED wait (never 0 in-loop), barrier
      if (i <= 15) {
        fill_group(WB4p, WY4p, ring, i + 2, wv, l);
        asm volatile("s_waitcnt vmcnt(10)" ::: "memory");  // fill(i+1) done
      } else {
        asm volatile("s_waitcnt vmcnt(0)" ::: "memory");   // drain tail
      }
      __builtin_amdgcn_sched_barrier(0);
      __builtin_amdgcn_s_barrier();
    } else {
      // consumer: barrier first (group i+1 now guaranteed), then compute
      __builtin_amdgcn_sched_barrier(0);
      __builtin_amdgcn_s_barrier();
      __builtin_amdgcn_sched_barrier(0);
      if (i) {
        // uniform renorm: 1/max(two band probes); bookkeeping in L
        const float r1 = rdlane(a1, tb >> 3);
        const float r2 = rdlane(a1, tb >> 2);
        const float rl = fmaxf(r1, r2);
        const float sc = (rl > 1e-30f) ? (1.0f / rl) : 1.0f;
        L -= __logf(sc);
        a1 *= sc; a2 *= sc; a3 *= sc; a4 *= sc;
        c1 *= sc; c2 *= sc; c3 *= sc; c4 *= sc;
      }
      // tb%15 == 1 always; FIFO loads pull slices tb+15..tb+29 (group i+1)
      // from ring slots rbB+0..14 (DMA'd during iteration i-1)
      const int rbB = 15 * ((i + 1) % 3);
      STEP(4,3,2,1,     rbB + 0,  tb + 15);
      STEP(5,4,3,2,     rbB + 1,  tb + 16);
      STEP(6,5,4,3,     rbB + 2,  tb + 17);
      STEP(7,6,5,4,     rbB + 3,  tb + 18);
      STEP(8,7,6,5,     rbB + 4,  tb + 19);
      STEP(9,8,7,6,     rbB + 5,  tb + 20);
      STEP(10,9,8,7,    rbB + 6,  tb + 21);
      STEP(11,10,9,8,   rbB + 7,  tb + 22);
      STEP(12,11,10,9,  rbB + 8,  tb + 23);
      STEP(13,12,11,10, rbB + 9,  tb + 24);
      STEP(14,13,12,11, rbB + 10, tb + 25);
      STEP(0,14,13,12,  rbB + 11, tb + 26);
      STEP(1,0,14,13,   rbB + 12, tb + 27);
      STEP(2,1,0,14,    rbB + 13, tb + 28);
      STEP(3,2,1,0,     rbB + 14, tb + 29);
    }
  }

  if (wv == 0 && l == 63) {
    // ll = L - SHIFT*256 + log( sum_d C[256-d] * WG_d ); G from LDS glds[tp]
    const float sum = c1 * glds[259].x
                    + c2 * glds[258].y
                    + c3 * glds[257].z
                    + c4 * glds[256].w;
    const float ll = L - SHIFT * 256.0f + __logf(sum);
    atomicAdd(out, ll * (-1.0f / TDT_B));
  }
#undef STEP
#undef LOADSLOT
}

extern "C" void kernel_launch(void* const* d_in, const int* in_sizes, int n_in,
                              void* d_out, int out_size, void* d_ws, size_t ws_size,
                              hipStream_t stream)
{
  const float* la = (const float*)d_in[0];   // label_acts    (B,T,U+1,V+1) f32
  const float* da = (const float*)d_in[1];   // duration_acts (B,T,U+1,D)   f32
  const int*   tg = (const int*)d_in[2];     // targets       (B,U)         i32
  float* ws  = (float*)d_ws;
  float* out = (float*)d_out;

  const int rows = TDT_B * TDT_T * TDT_U1;   // 133120
  k_prep<<<rows / 4, 256, 0, stream>>>(la, da, tg, ws, out);
  k_dp  <<<TDT_B, 256, (45 * 128 + TP) * sizeof(float4), stream>>>(ws, out);
}